// Round 13
// baseline (843.386 us; speedup 1.0000x reference)
//
#include <hip/hip_runtime.h>

typedef float f32x4 __attribute__((ext_vector_type(4)));
typedef unsigned int u32x4 __attribute__((ext_vector_type(4)));
typedef _Float16 f16x8 __attribute__((ext_vector_type(8)));
typedef unsigned short u16;
typedef unsigned int u32;

// ---- constants ----
#define NWIN 8192
#define WPB 4                     // windows per block (grid-stride amortization)
#define MAX_LOG_SCALE 4.605170185988091f  // log(100)
#define LOG2E 1.4426950408889634f

// Round-11 kernel (410 us) wrapped in a 4-window loop per block.
// Rationale: rounds 7/9/11 (three different structures) all converge at
// 410-413 us with all pipes <=36% and a ~10x gap between per-block residency
// (~107K cyc) and in-kernel critical path (~10-15K cyc) -> suspect per-block
// fixed overhead (dispatch/ramp) dominates. Amortize it 4x; single variable.
// Occupancy is reg-pinned at 4 waves/EU (rounds 4/6/10/12: any tighter cap
// spills ~0.4-1.5 GB scratch). LDS 24 KB: RX2 x2-staging -> O overlay; 2 KB
// wave-private bounce strip each.
#define RX2 0
#define RBNC 16384
#define LDS_BYTES 24576

__device__ __forceinline__ void mfma16(f32x4& acc, u32x4 a, u32x4 b) {
  acc = __builtin_amdgcn_mfma_f32_16x16x32_f16(
      __builtin_bit_cast(f16x8, a), __builtin_bit_cast(f16x8, b), acc, 0, 0, 0);
}

__device__ __forceinline__ u16 f2h(float f) {
  return __builtin_bit_cast(u16, (_Float16)f);
}
__device__ __forceinline__ u32 pkh(float x, float y) {  // packed f32->f16 (RTZ)
  return __builtin_bit_cast(u32, __builtin_amdgcn_cvt_pkrtz(x, y));
}

// XOR swizzle within a row (row stride 256B or 128B); bijective, stays in-row.
__device__ __forceinline__ int swz(int row, int colbyte) {
  return colbyte ^ ((row & 7) << 4);
}
__device__ __forceinline__ u32x4 ldsfrag(const char* p, int row, int colbyte, int stride) {
  return *(const u32x4*)(p + row * stride + swz(row, colbyte));
}
__device__ __forceinline__ void lds_st16(char* p, int row, int colbyte, int stride, u16 v) {
  *(u16*)(p + row * stride + swz(row, colbyte)) = v;
}
// small bounce [16][32] f16: padded stride 80B (banks spread, no swizzle)
__device__ __forceinline__ u32x4 bnc32_ld(const char* p, int row, int colbyte) {
  return *(const u32x4*)(p + row * 80 + colbyte);
}
__device__ __forceinline__ void bnc32_st(char* p, int row, int colbyte, u16 v) {
  *(u16*)(p + row * 80 + colbyte) = v;
}
__device__ __forceinline__ u32x4 gfrag(const u16* p) {
  return *(const u32x4*)p;
}
// f32 activation frag from global, converted to f16 in flight
__device__ __forceinline__ u32x4 gfrag32(const float* p) {
  float4 lo = *(const float4*)p;
  float4 hi = *(const float4*)(p + 4);
  u32x4 r = { pkh(lo.x, lo.y), pkh(lo.z, lo.w), pkh(hi.x, hi.y), pkh(hi.z, hi.w) };
  return r;
}

// ---------- weight prep: f32 -> f16 (contiguous qw|kvw|pw) + head scales ----------
__global__ void wca_prep(const float* __restrict__ qw, const float* __restrict__ kvw,
                         const float* __restrict__ pw, const float* __restrict__ ls,
                         u16* __restrict__ wh, float* __restrict__ scales) {
  int t = blockIdx.x * 256 + threadIdx.x;   // 0..16383, one float4 each
  int e = t * 4;
  const float* src;
  int off;
  if (e < 16384)      { src = qw;  off = e; }
  else if (e < 49152) { src = kvw; off = e - 16384; }
  else                { src = pw;  off = e - 49152; }
  float4 v = *(const float4*)(src + off);
  uint2 o = { pkh(v.x, v.y), pkh(v.z, v.w) };
  *(uint2*)(wh + e) = o;
  if (t < 4) scales[t] = __expf(fminf(ls[t], MAX_LOG_SCALE)) * LOG2E;
}

// ---------- main kernel: WPB windows per block, wave = head ----------
__global__ void __launch_bounds__(256, 4) wca_kernel(
    const float* __restrict__ x1, const float* __restrict__ x2,
    const float* __restrict__ qb, const float* __restrict__ vb,
    const float* __restrict__ pb, const u16* __restrict__ wh,
    const float* __restrict__ scales, float* __restrict__ out) {
  __shared__ char smem[LDS_BYTES];
  const int tid = threadIdx.x;
  const int wv = tid >> 6;          // wave = head 0..3
  const int lane = tid & 63;
  const int lr = lane & 15;
  const int lg = lane >> 4;
  const int h32 = wv * 32;
  const u16* qw_  = wh;                     // 128x128
  const u16* kvwk = wh + 16384;             // k-part rows 0..127
  const u16* kvwv = wh + 16384 + 16384;     // v-part rows 0..127
  const u16* pw_  = wh + 49152;             // 128x128
  char* bnc = smem + RBNC + wv * 2048;      // wave-private bounce strip
  const float sc = scales[wv];              // includes log2(e)
  const float qb0 = qb[h32 + lr], qb1 = qb[h32 + 16 + lr];

  for (int w = 0; w < WPB; ++w) {
    const int b = blockIdx.x * WPB + w;
    const float* x1w = x1 + (size_t)b * 8192;
    const float* x2w = x2 + (size_t)b * 8192;

    __syncthreads();  // (0) prev window's proj reads of RX2 (O) complete

    // ---- phase 0: stage x2 -> f16 LDS (8 loads/thread hoisted) ----
    {
      const float4* p2 = (const float4*)x2w;
      float4 c[8];
#pragma unroll
      for (int i = 0; i < 8; ++i) c[i] = p2[i * 256 + tid];
#pragma unroll
      for (int i = 0; i < 8; ++i) {
        int e = (i * 256 + tid) * 4;
        int row = e >> 7;
        int colb = (e & 127) * 2;
        uint2 pc = { pkh(c[i].x, c[i].y), pkh(c[i].z, c[i].w) };
        *(uint2*)(smem + RX2 + row * 256 + swz(row, colb)) = pc;
      }
    }
    __syncthreads();  // (1) x2 visible

    // ---- V pass: vT(c,m) = sum_k kvw_v[h32+c][k]*x2[m][k] + vb ----
    u32x4 bv[2][2];
#pragma unroll
    for (int jt = 0; jt < 2; ++jt) {
      u32x4 akv[4];
#pragma unroll
      for (int kc = 0; kc < 4; ++kc)
        akv[kc] = gfrag(kvwv + (h32 + jt * 16 + lr) * 128 + kc * 32 + lg * 8);
      f32x4 vc[4];
#pragma unroll
      for (int nt = 0; nt < 4; ++nt) vc[nt] = (f32x4){0.f, 0.f, 0.f, 0.f};
#pragma unroll
      for (int nt = 0; nt < 4; ++nt) {
        u32x4 bx[4];
#pragma unroll
        for (int kc = 0; kc < 4; ++kc)
          bx[kc] = ldsfrag(smem + RX2, nt * 16 + lr, kc * 64 + lg * 16, 256);
#pragma unroll
        for (int kc = 0; kc < 4; ++kc) mfma16(vc[nt], akv[kc], bx[kc]);
      }
      float vbias[4];
#pragma unroll
      for (int i = 0; i < 4; ++i) vbias[i] = vb[h32 + jt * 16 + lg * 4 + i];
#pragma unroll
      for (int nt = 0; nt < 4; ++nt)
#pragma unroll
        for (int i = 0; i < 4; ++i)
          lds_st16(bnc, lg * 4 + i, (nt * 16 + lr) * 2, 128, f2h(vc[nt][i] + vbias[i]));
#pragma unroll
      for (int kc = 0; kc < 2; ++kc)
        bv[jt][kc] = ldsfrag(bnc, lr, kc * 64 + lg * 16, 128);  // wave-local RAW
    }

    // ---- K pass: k rows m, L2-normalized -> bk[mt] ----
    u32x4 bk[4];
    {
      u32x4 bkw[2][4];
#pragma unroll
      for (int jt = 0; jt < 2; ++jt)
#pragma unroll
        for (int kc = 0; kc < 4; ++kc)
          bkw[jt][kc] = gfrag(kvwk + (h32 + jt * 16 + lr) * 128 + kc * 32 + lg * 8);
#pragma unroll
      for (int mt = 0; mt < 4; ++mt) {
        f32x4 c0 = {0.f, 0.f, 0.f, 0.f}, c1 = {0.f, 0.f, 0.f, 0.f};
#pragma unroll
        for (int kc = 0; kc < 4; ++kc) {
          u32x4 ax = ldsfrag(smem + RX2, mt * 16 + lr, kc * 64 + lg * 16, 256);
          mfma16(c0, ax, bkw[0][kc]);
          mfma16(c1, ax, bkw[1][kc]);
        }
        float s[4];
#pragma unroll
        for (int i = 0; i < 4; ++i) s[i] = c0[i] * c0[i] + c1[i] * c1[i];
#pragma unroll
        for (int m = 1; m < 16; m <<= 1)
#pragma unroll
          for (int i = 0; i < 4; ++i) s[i] += __shfl_xor(s[i], m, 64);
#pragma unroll
        for (int i = 0; i < 4; ++i) {
          float rn = 1.0f / fmaxf(sqrtf(s[i]), 1e-12f);
          bnc32_st(bnc, lg * 4 + i, lr * 2, f2h(c0[i] * rn));
          bnc32_st(bnc, lg * 4 + i, (16 + lr) * 2, f2h(c1[i] * rn));
        }
        bk[mt] = bnc32_ld(bnc, lr, lg * 16);  // wave-local RAW
      }
    }
    __syncthreads();  // (2) all waves done reading x2 -> O may overlay RX2

    // ---- Q + attention per nt (deferred q-norm and softmax-div) ----
#pragma unroll
    for (int nt = 0; nt < 4; ++nt) {
      f32x4 q0 = {0.f, 0.f, 0.f, 0.f}, q1 = {0.f, 0.f, 0.f, 0.f};
#pragma unroll
      for (int kc = 0; kc < 4; ++kc) {
        u32x4 a = gfrag32(x1w + (nt * 16 + lr) * 128 + kc * 32 + lg * 8);
        u32x4 w0 = gfrag(qw_ + (h32 + lr) * 128 + kc * 32 + lg * 8);
        u32x4 w1 = gfrag(qw_ + (h32 + 16 + lr) * 128 + kc * 32 + lg * 8);
        mfma16(q0, a, w0);
        mfma16(q1, a, w1);
      }
      // bias, store biased UNNORMALIZED q; shuffle-reduce overlaps the RAW trip
#pragma unroll
      for (int i = 0; i < 4; ++i) { q0[i] += qb0; q1[i] += qb1; }
#pragma unroll
      for (int i = 0; i < 4; ++i) {
        bnc32_st(bnc, lg * 4 + i, lr * 2, f2h(q0[i]));
        bnc32_st(bnc, lg * 4 + i, (16 + lr) * 2, f2h(q1[i]));
      }
      float s[4];
#pragma unroll
      for (int i = 0; i < 4; ++i) s[i] = q0[i] * q0[i] + q1[i] * q1[i];
#pragma unroll
      for (int m = 1; m < 16; m <<= 1)
#pragma unroll
        for (int i = 0; i < 4; ++i) s[i] += __shfl_xor(s[i], m, 64);
      float scrn[4];  // sc/||q||: folds q-normalization into exp2 argument
#pragma unroll
      for (int i = 0; i < 4; ++i) scrn[i] = sc / fmaxf(sqrtf(s[i]), 1e-12f);
      u32x4 aq = bnc32_ld(bnc, lr, lg * 16);  // wave-local RAW

      f32x4 att[4];
#pragma unroll
      for (int mt = 0; mt < 4; ++mt) {
        f32x4 z = {0.f, 0.f, 0.f, 0.f};
        mfma16(z, aq, bk[mt]);
        att[mt] = z;
      }
      // p = exp2(att_raw*sc*rn - sc); logits <= sc bound (no max reduce).
#pragma unroll
      for (int i = 0; i < 4; ++i)
#pragma unroll
        for (int mt = 0; mt < 4; ++mt)
          att[mt][i] = exp2f(fmaf(att[mt][i], scrn[i], -sc));
#pragma unroll
      for (int i = 0; i < 4; ++i)
#pragma unroll
        for (int mt = 0; mt < 4; ++mt)
          lds_st16(bnc, lg * 4 + i, (mt * 16 + lr) * 2, 128, f2h(att[mt][i]));
      float sum[4] = {0.f, 0.f, 0.f, 0.f};
#pragma unroll
      for (int i = 0; i < 4; ++i)
#pragma unroll
        for (int mt = 0; mt < 4; ++mt) sum[i] += att[mt][i];
#pragma unroll
      for (int m = 1; m < 16; m <<= 1)
#pragma unroll
        for (int i = 0; i < 4; ++i) sum[i] += __shfl_xor(sum[i], m, 64);
      float rs[4];
#pragma unroll
      for (int i = 0; i < 4; ++i) rs[i] = 1.0f / sum[i];

      u32x4 ap[2];
#pragma unroll
      for (int kc = 0; kc < 2; ++kc)
        ap[kc] = ldsfrag(bnc, lr, kc * 64 + lg * 16, 128);  // wave-local RAW
#pragma unroll
      for (int ct = 0; ct < 2; ++ct) {
        f32x4 z = {0.f, 0.f, 0.f, 0.f};
#pragma unroll
        for (int kc = 0; kc < 2; ++kc) mfma16(z, ap[kc], bv[ct][kc]);
        // deferred softmax division folded into O store
#pragma unroll
        for (int i = 0; i < 4; ++i)
          lds_st16(smem + RX2, nt * 16 + lg * 4 + i, (h32 + ct * 16 + lr) * 2, 256,
                   f2h(z[i] * rs[i]));
      }
    }

    // hoist proj weight frags (L2) to overlap with the barrier
    u32x4 bp[2][4];
#pragma unroll
    for (int ct = 0; ct < 2; ++ct)
#pragma unroll
      for (int kc = 0; kc < 4; ++kc)
        bp[ct][kc] = gfrag(pw_ + (h32 + ct * 16 + lr) * 128 + kc * 32 + lg * 8);
    float pbv[2] = { pb[h32 + lr], pb[h32 + 16 + lr] };

    __syncthreads();  // (3) O complete

    // ---- proj (column-scheme): out[:, h32..h32+32) = O @ pw[own rows]^T + pb ----
    {
      float* ob = out + (size_t)b * 8192;
#pragma unroll
      for (int np = 0; np < 2; ++np) {
        u32x4 af[2][4];
#pragma unroll
        for (int t = 0; t < 2; ++t)
#pragma unroll
          for (int kc = 0; kc < 4; ++kc)
            af[t][kc] = ldsfrag(smem + RX2, (np * 2 + t) * 16 + lr, kc * 64 + lg * 16, 256);
#pragma unroll
        for (int t = 0; t < 2; ++t)
#pragma unroll
          for (int ct = 0; ct < 2; ++ct) {
            f32x4 acc = {0.f, 0.f, 0.f, 0.f};
#pragma unroll
            for (int kc = 0; kc < 4; ++kc) mfma16(acc, af[t][kc], bp[ct][kc]);
#pragma unroll
            for (int i = 0; i < 4; ++i) {
              int row = (np * 2 + t) * 16 + lg * 4 + i;
              ob[row * 128 + h32 + ct * 16 + lr] = acc[i] + pbv[ct];
            }
          }
      }
    }
  }
}

extern "C" void kernel_launch(void* const* d_in, const int* in_sizes, int n_in,
                              void* d_out, int out_size, void* d_ws, size_t ws_size,
                              hipStream_t stream) {
  const float* x1 = (const float*)d_in[0];
  const float* x2 = (const float*)d_in[1];
  const float* qw = (const float*)d_in[2];
  const float* qb = (const float*)d_in[3];
  const float* kvw = (const float*)d_in[4];
  const float* vb = (const float*)d_in[5];
  const float* ls = (const float*)d_in[6];
  const float* pw = (const float*)d_in[7];
  const float* pb = (const float*)d_in[8];
  u16* wh = (u16*)d_ws;                           // 65536 f16 = 128 KB
  float* scales = (float*)((char*)d_ws + 131072); // 4 floats

  wca_prep<<<64, 256, 0, stream>>>(qw, kvw, pw, ls, wh, scales);
  wca_kernel<<<NWIN / WPB, 256, 0, stream>>>(x1, x2, qb, vb, pb, wh, scales,
                                             (float*)d_out);
}

// Round 14
// 316.398 us; speedup vs baseline: 2.6656x; 2.6656x over previous
//
#include <hip/hip_runtime.h>

typedef float f32x4 __attribute__((ext_vector_type(4)));
typedef unsigned int u32x4 __attribute__((ext_vector_type(4)));
typedef _Float16 f16x8 __attribute__((ext_vector_type(8)));
typedef unsigned short u16;
typedef unsigned int u32;

// ---- constants ----
#define NWIN 8192
#define MAX_LOG_SCALE 4.605170185988091f  // log(100)
#define LOG2E 1.4426950408889634f

// Wave = head end-to-end; 3 barriers; launch_bounds(256,4) (reg-pinned: unified
// VGPR+AGPR live state ~128/wave; tighter caps spill — proven rounds 4/6/10/12).
// This round: stage x1 in LDS too (round-13's WPB experiment falsified launch
// overhead; the remaining critical-path component is the per-nt x1 HBM load
// feeding the q-MFMA directly: ~600-900 cyc x 4 per wave, plus 4x redundant
// per-wave re-reads of x1). Phase 0 now stages BOTH tensors with one batched
// latency event; attention reads x1 from LDS (~120 cyc, pipelined).
// LDS (40 KB -> 4 blocks/CU, matches reg pin):
//   RX1  [0,16K):   x1 f16 [64][128] swz (read by all waves in Q phase)
//   RX2  [16K,32K): x2 f16 [64][128] swz -> O overlay after barrier (2)
//   RBNC [32K,40K): per-wave 2 KB bounce strip (vT -> k -> q -> P, wave-local)
#define RX1 0
#define RX2 16384
#define RBNC 32768
#define LDS_BYTES 40960

__device__ __forceinline__ void mfma16(f32x4& acc, u32x4 a, u32x4 b) {
  acc = __builtin_amdgcn_mfma_f32_16x16x32_f16(
      __builtin_bit_cast(f16x8, a), __builtin_bit_cast(f16x8, b), acc, 0, 0, 0);
}

__device__ __forceinline__ u16 f2h(float f) {
  return __builtin_bit_cast(u16, (_Float16)f);
}
__device__ __forceinline__ u32 pkh(float x, float y) {  // packed f32->f16 (RTZ)
  return __builtin_bit_cast(u32, __builtin_amdgcn_cvt_pkrtz(x, y));
}

// XOR swizzle within a row (row stride 256B or 128B); bijective, stays in-row.
__device__ __forceinline__ int swz(int row, int colbyte) {
  return colbyte ^ ((row & 7) << 4);
}
__device__ __forceinline__ u32x4 ldsfrag(const char* p, int row, int colbyte, int stride) {
  return *(const u32x4*)(p + row * stride + swz(row, colbyte));
}
__device__ __forceinline__ void lds_st16(char* p, int row, int colbyte, int stride, u16 v) {
  *(u16*)(p + row * stride + swz(row, colbyte)) = v;
}
// small bounce [16][32] f16: padded stride 80B (banks spread, no swizzle)
__device__ __forceinline__ u32x4 bnc32_ld(const char* p, int row, int colbyte) {
  return *(const u32x4*)(p + row * 80 + colbyte);
}
__device__ __forceinline__ void bnc32_st(char* p, int row, int colbyte, u16 v) {
  *(u16*)(p + row * 80 + colbyte) = v;
}
__device__ __forceinline__ u32x4 gfrag(const u16* p) {
  return *(const u32x4*)p;
}

// ---------- weight prep: f32 -> f16 (contiguous qw|kvw|pw) + head scales ----------
__global__ void wca_prep(const float* __restrict__ qw, const float* __restrict__ kvw,
                         const float* __restrict__ pw, const float* __restrict__ ls,
                         u16* __restrict__ wh, float* __restrict__ scales) {
  int t = blockIdx.x * 256 + threadIdx.x;   // 0..16383, one float4 each
  int e = t * 4;
  const float* src;
  int off;
  if (e < 16384)      { src = qw;  off = e; }
  else if (e < 49152) { src = kvw; off = e - 16384; }
  else                { src = pw;  off = e - 49152; }
  float4 v = *(const float4*)(src + off);
  uint2 o = { pkh(v.x, v.y), pkh(v.z, v.w) };
  *(uint2*)(wh + e) = o;
  if (t < 4) scales[t] = __expf(fminf(ls[t], MAX_LOG_SCALE)) * LOG2E;
}

// ---------- main kernel: one window per block, wave = head, 3 barriers ----------
__global__ void __launch_bounds__(256, 4) wca_kernel(
    const float* __restrict__ x1, const float* __restrict__ x2,
    const float* __restrict__ qb, const float* __restrict__ vb,
    const float* __restrict__ pb, const u16* __restrict__ wh,
    const float* __restrict__ scales, float* __restrict__ out) {
  __shared__ char smem[LDS_BYTES];
  const int b = blockIdx.x;
  const int tid = threadIdx.x;
  const int wv = tid >> 6;          // wave = head 0..3
  const int lane = tid & 63;
  const int lr = lane & 15;
  const int lg = lane >> 4;
  const int h32 = wv * 32;
  const u16* qw_  = wh;                     // 128x128
  const u16* kvwk = wh + 16384;             // k-part rows 0..127
  const u16* kvwv = wh + 16384 + 16384;     // v-part rows 0..127
  const u16* pw_  = wh + 49152;             // 128x128
  char* bnc = smem + RBNC + wv * 2048;      // wave-private bounce strip

  // ---- phase 0: stage x1 AND x2 -> f16 LDS (all 16 loads hoisted) ----
  {
    const float4* p1 = (const float4*)(x1 + (size_t)b * 8192);
    const float4* p2 = (const float4*)(x2 + (size_t)b * 8192);
    float4 a[8], c[8];
#pragma unroll
    for (int i = 0; i < 8; ++i) { a[i] = p1[i * 256 + tid]; c[i] = p2[i * 256 + tid]; }
#pragma unroll
    for (int i = 0; i < 8; ++i) {
      int e = (i * 256 + tid) * 4;
      int row = e >> 7;
      int colb = (e & 127) * 2;
      uint2 pa = { pkh(a[i].x, a[i].y), pkh(a[i].z, a[i].w) };
      uint2 pc = { pkh(c[i].x, c[i].y), pkh(c[i].z, c[i].w) };
      *(uint2*)(smem + RX1 + row * 256 + swz(row, colb)) = pa;
      *(uint2*)(smem + RX2 + row * 256 + swz(row, colb)) = pc;
    }
  }
  __syncthreads();  // (1) x1,x2 visible

  // ---- V pass: vT(c,m) = sum_k kvw_v[h32+c][k]*x2[m][k] + vb (akv streamed) ----
  u32x4 bv[2][2];
#pragma unroll
  for (int jt = 0; jt < 2; ++jt) {
    u32x4 akv[4];
#pragma unroll
    for (int kc = 0; kc < 4; ++kc)
      akv[kc] = gfrag(kvwv + (h32 + jt * 16 + lr) * 128 + kc * 32 + lg * 8);
    f32x4 vc[4];
#pragma unroll
    for (int nt = 0; nt < 4; ++nt) vc[nt] = (f32x4){0.f, 0.f, 0.f, 0.f};
#pragma unroll
    for (int nt = 0; nt < 4; ++nt) {
      u32x4 bx[4];
#pragma unroll
      for (int kc = 0; kc < 4; ++kc)
        bx[kc] = ldsfrag(smem + RX2, nt * 16 + lr, kc * 64 + lg * 16, 256);
#pragma unroll
      for (int kc = 0; kc < 4; ++kc) mfma16(vc[nt], akv[kc], bx[kc]);
    }
    float vbias[4];
#pragma unroll
    for (int i = 0; i < 4; ++i) vbias[i] = vb[h32 + jt * 16 + lg * 4 + i];
#pragma unroll
    for (int nt = 0; nt < 4; ++nt)
#pragma unroll
      for (int i = 0; i < 4; ++i)
        lds_st16(bnc, lg * 4 + i, (nt * 16 + lr) * 2, 128, f2h(vc[nt][i] + vbias[i]));
#pragma unroll
    for (int kc = 0; kc < 2; ++kc)
      bv[jt][kc] = ldsfrag(bnc, lr, kc * 64 + lg * 16, 128);  // wave-local RAW
  }

  // ---- K pass: k rows m, L2-normalized -> bk[mt] ----
  u32x4 bk[4];
  {
    u32x4 bkw[2][4];
#pragma unroll
    for (int jt = 0; jt < 2; ++jt)
#pragma unroll
      for (int kc = 0; kc < 4; ++kc)
        bkw[jt][kc] = gfrag(kvwk + (h32 + jt * 16 + lr) * 128 + kc * 32 + lg * 8);
#pragma unroll
    for (int mt = 0; mt < 4; ++mt) {
      f32x4 c0 = {0.f, 0.f, 0.f, 0.f}, c1 = {0.f, 0.f, 0.f, 0.f};
#pragma unroll
      for (int kc = 0; kc < 4; ++kc) {
        u32x4 ax = ldsfrag(smem + RX2, mt * 16 + lr, kc * 64 + lg * 16, 256);
        mfma16(c0, ax, bkw[0][kc]);
        mfma16(c1, ax, bkw[1][kc]);
      }
      float s[4];
#pragma unroll
      for (int i = 0; i < 4; ++i) s[i] = c0[i] * c0[i] + c1[i] * c1[i];
#pragma unroll
      for (int m = 1; m < 16; m <<= 1)
#pragma unroll
        for (int i = 0; i < 4; ++i) s[i] += __shfl_xor(s[i], m, 64);
#pragma unroll
      for (int i = 0; i < 4; ++i) {
        float rn = 1.0f / fmaxf(sqrtf(s[i]), 1e-12f);
        bnc32_st(bnc, lg * 4 + i, lr * 2, f2h(c0[i] * rn));
        bnc32_st(bnc, lg * 4 + i, (16 + lr) * 2, f2h(c1[i] * rn));
      }
      bk[mt] = bnc32_ld(bnc, lr, lg * 16);  // wave-local RAW
    }
  }
  __syncthreads();  // (2) all waves done reading x2 -> O may overlay RX2

  // ---- Q + attention per nt (x1 from LDS; deferred q-norm and softmax-div) ----
  const float sc = scales[wv];  // includes log2(e)
  const float qb0 = qb[h32 + lr], qb1 = qb[h32 + 16 + lr];
#pragma unroll
  for (int nt = 0; nt < 4; ++nt) {
    f32x4 q0 = {0.f, 0.f, 0.f, 0.f}, q1 = {0.f, 0.f, 0.f, 0.f};
#pragma unroll
    for (int kc = 0; kc < 4; ++kc) {
      u32x4 a = ldsfrag(smem + RX1, nt * 16 + lr, kc * 64 + lg * 16, 256);
      u32x4 w0 = gfrag(qw_ + (h32 + lr) * 128 + kc * 32 + lg * 8);
      u32x4 w1 = gfrag(qw_ + (h32 + 16 + lr) * 128 + kc * 32 + lg * 8);
      mfma16(q0, a, w0);
      mfma16(q1, a, w1);
    }
    // bias, store biased UNNORMALIZED q; shuffle-reduce overlaps the RAW trip
#pragma unroll
    for (int i = 0; i < 4; ++i) { q0[i] += qb0; q1[i] += qb1; }
#pragma unroll
    for (int i = 0; i < 4; ++i) {
      bnc32_st(bnc, lg * 4 + i, lr * 2, f2h(q0[i]));
      bnc32_st(bnc, lg * 4 + i, (16 + lr) * 2, f2h(q1[i]));
    }
    float s[4];
#pragma unroll
    for (int i = 0; i < 4; ++i) s[i] = q0[i] * q0[i] + q1[i] * q1[i];
#pragma unroll
    for (int m = 1; m < 16; m <<= 1)
#pragma unroll
      for (int i = 0; i < 4; ++i) s[i] += __shfl_xor(s[i], m, 64);
    float scrn[4];  // sc/||q||: folds q-normalization into exp2 argument
#pragma unroll
    for (int i = 0; i < 4; ++i) scrn[i] = sc / fmaxf(sqrtf(s[i]), 1e-12f);
    u32x4 aq = bnc32_ld(bnc, lr, lg * 16);  // wave-local RAW

    f32x4 att[4];
#pragma unroll
    for (int mt = 0; mt < 4; ++mt) {
      f32x4 z = {0.f, 0.f, 0.f, 0.f};
      mfma16(z, aq, bk[mt]);
      att[mt] = z;
    }
    // p = exp2(att_raw*sc*rn - sc); logits <= sc bound (no max reduce).
#pragma unroll
    for (int i = 0; i < 4; ++i)
#pragma unroll
      for (int mt = 0; mt < 4; ++mt)
        att[mt][i] = exp2f(fmaf(att[mt][i], scrn[i], -sc));
#pragma unroll
    for (int i = 0; i < 4; ++i)
#pragma unroll
      for (int mt = 0; mt < 4; ++mt)
        lds_st16(bnc, lg * 4 + i, (mt * 16 + lr) * 2, 128, f2h(att[mt][i]));
    float sum[4] = {0.f, 0.f, 0.f, 0.f};
#pragma unroll
    for (int i = 0; i < 4; ++i)
#pragma unroll
      for (int mt = 0; mt < 4; ++mt) sum[i] += att[mt][i];
#pragma unroll
    for (int m = 1; m < 16; m <<= 1)
#pragma unroll
      for (int i = 0; i < 4; ++i) sum[i] += __shfl_xor(sum[i], m, 64);
    float rs[4];
#pragma unroll
    for (int i = 0; i < 4; ++i) rs[i] = 1.0f / sum[i];

    u32x4 ap[2];
#pragma unroll
    for (int kc = 0; kc < 2; ++kc)
      ap[kc] = ldsfrag(bnc, lr, kc * 64 + lg * 16, 128);  // wave-local RAW
#pragma unroll
    for (int ct = 0; ct < 2; ++ct) {
      f32x4 z = {0.f, 0.f, 0.f, 0.f};
#pragma unroll
      for (int kc = 0; kc < 2; ++kc) mfma16(z, ap[kc], bv[ct][kc]);
      // deferred softmax division folded into O store
#pragma unroll
      for (int i = 0; i < 4; ++i)
        lds_st16(smem + RX2, nt * 16 + lg * 4 + i, (h32 + ct * 16 + lr) * 2, 256,
                 f2h(z[i] * rs[i]));
    }
  }

  // hoist proj weight frags (L2) to overlap with the barrier
  u32x4 bp[2][4];
#pragma unroll
  for (int ct = 0; ct < 2; ++ct)
#pragma unroll
    for (int kc = 0; kc < 4; ++kc)
      bp[ct][kc] = gfrag(pw_ + (h32 + ct * 16 + lr) * 128 + kc * 32 + lg * 8);
  float pbv[2] = { pb[h32 + lr], pb[h32 + 16 + lr] };

  __syncthreads();  // (3) O complete

  // ---- proj (column-scheme): out[:, h32..h32+32) = O @ pw[own rows]^T + pb ----
  {
    float* ob = out + (size_t)b * 8192;
#pragma unroll
    for (int np = 0; np < 2; ++np) {
      u32x4 af[2][4];
#pragma unroll
      for (int t = 0; t < 2; ++t)
#pragma unroll
        for (int kc = 0; kc < 4; ++kc)
          af[t][kc] = ldsfrag(smem + RX2, (np * 2 + t) * 16 + lr, kc * 64 + lg * 16, 256);
#pragma unroll
      for (int t = 0; t < 2; ++t)
#pragma unroll
        for (int ct = 0; ct < 2; ++ct) {
          f32x4 acc = {0.f, 0.f, 0.f, 0.f};
#pragma unroll
          for (int kc = 0; kc < 4; ++kc) mfma16(acc, af[t][kc], bp[ct][kc]);
#pragma unroll
          for (int i = 0; i < 4; ++i) {
            int row = (np * 2 + t) * 16 + lg * 4 + i;
            ob[row * 128 + h32 + ct * 16 + lr] = acc[i] + pbv[ct];
          }
        }
    }
  }
}

extern "C" void kernel_launch(void* const* d_in, const int* in_sizes, int n_in,
                              void* d_out, int out_size, void* d_ws, size_t ws_size,
                              hipStream_t stream) {
  const float* x1 = (const float*)d_in[0];
  const float* x2 = (const float*)d_in[1];
  const float* qw = (const float*)d_in[2];
  const float* qb = (const float*)d_in[3];
  const float* kvw = (const float*)d_in[4];
  const float* vb = (const float*)d_in[5];
  const float* ls = (const float*)d_in[6];
  const float* pw = (const float*)d_in[7];
  const float* pb = (const float*)d_in[8];
  u16* wh = (u16*)d_ws;                           // 65536 f16 = 128 KB
  float* scales = (float*)((char*)d_ws + 131072); // 4 floats

  wca_prep<<<64, 256, 0, stream>>>(qw, kvw, pw, ls, wh, scales);
  wca_kernel<<<NWIN, 256, 0, stream>>>(x1, x2, qb, vb, pb, wh, scales, (float*)d_out);
}

// Round 17
// 306.295 us; speedup vs baseline: 2.7535x; 1.0330x over previous
//
#include <hip/hip_runtime.h>

typedef float f32x4 __attribute__((ext_vector_type(4)));
typedef unsigned int u32x4 __attribute__((ext_vector_type(4)));
typedef _Float16 f16x8 __attribute__((ext_vector_type(8)));
typedef unsigned short u16;
typedef unsigned int u32;

// ---- constants ----
#define NWIN 8192
#define MAX_LOG_SCALE 4.605170185988091f  // log(100)
#define LOG2E 1.4426950408889634f

// Wave = head end-to-end; 3 barriers; launch_bounds(256,4) (reg-pinned ~128
// unified regs/wave; tighter caps spill — rounds 4/6/10/12).
// Round 17 = swapped QK^T kept, ALL cross-32-lane shuffles removed.
// Forensics: R15/R16 failed with IDENTICAL absmax (1.828125) despite different
// P paths -> shared fault. The swap is proven safe (R14 passing with random
// inputs characterizes the MFMA bilinear map for arbitrary frag contents);
// the shared novelty is __shfl_xor with masks 16/32 (first use ever; all
// passing kernels used masks 1/2/4/8 only). This round:
//  - q-norm: R14's PROVEN mask-1/2/4/8 tree on f32 projections; store
//    NORMALIZED q -> exp scale is constant sc again
//  - softmax sum over lg-groups: 256B wave-private LDS exchange
//    (ds_write_b32 + ds_read_b128, in-order) instead of shfl_xor 16/32
// LDS (40 KB -> 4 blocks/CU):
//   RX1  [0,16K):   x1 f16 [64][128] swz
//   RX2  [16K,32K): x2 f16 [64][128] swz -> O overlay after barrier (2)
//   RBNC [32K,40K): per-wave 2 KB strip (vT -> k -> q -> P + pex@1792)
#define RX1 0
#define RX2 16384
#define RBNC 32768
#define LDS_BYTES 40960

__device__ __forceinline__ void mfma16(f32x4& acc, u32x4 a, u32x4 b) {
  acc = __builtin_amdgcn_mfma_f32_16x16x32_f16(
      __builtin_bit_cast(f16x8, a), __builtin_bit_cast(f16x8, b), acc, 0, 0, 0);
}

__device__ __forceinline__ u16 f2h(float f) {
  return __builtin_bit_cast(u16, (_Float16)f);
}
__device__ __forceinline__ u32 pkh(float x, float y) {  // packed f32->f16 (RTZ)
  return __builtin_bit_cast(u32, __builtin_amdgcn_cvt_pkrtz(x, y));
}

// XOR swizzle within a row (row stride 256B or 128B); bijective, stays in-row.
__device__ __forceinline__ int swz(int row, int colbyte) {
  return colbyte ^ ((row & 7) << 4);
}
__device__ __forceinline__ u32x4 ldsfrag(const char* p, int row, int colbyte, int stride) {
  return *(const u32x4*)(p + row * stride + swz(row, colbyte));
}
__device__ __forceinline__ void lds_st16(char* p, int row, int colbyte, int stride, u16 v) {
  *(u16*)(p + row * stride + swz(row, colbyte)) = v;
}
// small bounce [16][32] f16: padded stride 80B (banks spread, no swizzle)
__device__ __forceinline__ u32x4 bnc32_ld(const char* p, int row, int colbyte) {
  return *(const u32x4*)(p + row * 80 + colbyte);
}
__device__ __forceinline__ void bnc32_st(char* p, int row, int colbyte, u16 v) {
  *(u16*)(p + row * 80 + colbyte) = v;
}
__device__ __forceinline__ u32x4 gfrag(const u16* p) {
  return *(const u32x4*)p;
}

// ---------- weight prep: f32 -> f16 (contiguous qw|kvw|pw) + head scales ----------
__global__ void wca_prep(const float* __restrict__ qw, const float* __restrict__ kvw,
                         const float* __restrict__ pw, const float* __restrict__ ls,
                         u16* __restrict__ wh, float* __restrict__ scales) {
  int t = blockIdx.x * 256 + threadIdx.x;   // 0..16383, one float4 each
  int e = t * 4;
  const float* src;
  int off;
  if (e < 16384)      { src = qw;  off = e; }
  else if (e < 49152) { src = kvw; off = e - 16384; }
  else                { src = pw;  off = e - 49152; }
  float4 v = *(const float4*)(src + off);
  uint2 o = { pkh(v.x, v.y), pkh(v.z, v.w) };
  *(uint2*)(wh + e) = o;
  if (t < 4) scales[t] = __expf(fminf(ls[t], MAX_LOG_SCALE)) * LOG2E;
}

// ---------- main kernel: one window per block, wave = head, 3 barriers ----------
__global__ void __launch_bounds__(256, 4) wca_kernel(
    const float* __restrict__ x1, const float* __restrict__ x2,
    const float* __restrict__ qb, const float* __restrict__ vb,
    const float* __restrict__ pb, const u16* __restrict__ wh,
    const float* __restrict__ scales, float* __restrict__ out) {
  __shared__ char smem[LDS_BYTES];
  const int b = blockIdx.x;
  const int tid = threadIdx.x;
  const int wv = tid >> 6;          // wave = head 0..3
  const int lane = tid & 63;
  const int lr = lane & 15;
  const int lg = lane >> 4;
  const int h32 = wv * 32;
  const u16* qw_  = wh;                     // 128x128
  const u16* kvwk = wh + 16384;             // k-part rows 0..127
  const u16* kvwv = wh + 16384 + 16384;     // v-part rows 0..127
  const u16* pw_  = wh + 49152;             // 128x128
  char* bnc = smem + RBNC + wv * 2048;      // wave-private bounce strip
  char* pex = bnc + 1792;                   // 256B partial-sum exchange area

  // ---- phase 0: stage x1 AND x2 -> f16 LDS (all 16 loads hoisted) ----
  {
    const float4* p1 = (const float4*)(x1 + (size_t)b * 8192);
    const float4* p2 = (const float4*)(x2 + (size_t)b * 8192);
    float4 a[8], c[8];
#pragma unroll
    for (int i = 0; i < 8; ++i) { a[i] = p1[i * 256 + tid]; c[i] = p2[i * 256 + tid]; }
#pragma unroll
    for (int i = 0; i < 8; ++i) {
      int e = (i * 256 + tid) * 4;
      int row = e >> 7;
      int colb = (e & 127) * 2;
      uint2 pa = { pkh(a[i].x, a[i].y), pkh(a[i].z, a[i].w) };
      uint2 pc = { pkh(c[i].x, c[i].y), pkh(c[i].z, c[i].w) };
      *(uint2*)(smem + RX1 + row * 256 + swz(row, colb)) = pa;
      *(uint2*)(smem + RX2 + row * 256 + swz(row, colb)) = pc;
    }
  }
  __syncthreads();  // (1) x1,x2 visible

  // ---- V pass: vT(c,m) = sum_k kvw_v[h32+c][k]*x2[m][k] + vb (akv streamed) ----
  u32x4 bv[2][2];
#pragma unroll
  for (int jt = 0; jt < 2; ++jt) {
    u32x4 akv[4];
#pragma unroll
    for (int kc = 0; kc < 4; ++kc)
      akv[kc] = gfrag(kvwv + (h32 + jt * 16 + lr) * 128 + kc * 32 + lg * 8);
    f32x4 vc[4];
#pragma unroll
    for (int nt = 0; nt < 4; ++nt) vc[nt] = (f32x4){0.f, 0.f, 0.f, 0.f};
#pragma unroll
    for (int nt = 0; nt < 4; ++nt) {
      u32x4 bx[4];
#pragma unroll
      for (int kc = 0; kc < 4; ++kc)
        bx[kc] = ldsfrag(smem + RX2, nt * 16 + lr, kc * 64 + lg * 16, 256);
#pragma unroll
      for (int kc = 0; kc < 4; ++kc) mfma16(vc[nt], akv[kc], bx[kc]);
    }
    float vbias[4];
#pragma unroll
    for (int i = 0; i < 4; ++i) vbias[i] = vb[h32 + jt * 16 + lg * 4 + i];
#pragma unroll
    for (int nt = 0; nt < 4; ++nt)
#pragma unroll
      for (int i = 0; i < 4; ++i)
        lds_st16(bnc, lg * 4 + i, (nt * 16 + lr) * 2, 128, f2h(vc[nt][i] + vbias[i]));
#pragma unroll
    for (int kc = 0; kc < 2; ++kc)
      bv[jt][kc] = ldsfrag(bnc, lr, kc * 64 + lg * 16, 128);  // wave-local RAW
  }

  // ---- K pass: k rows m, L2-normalized -> bk[mt] ----
  u32x4 bk[4];
  {
    u32x4 bkw[2][4];
#pragma unroll
    for (int jt = 0; jt < 2; ++jt)
#pragma unroll
      for (int kc = 0; kc < 4; ++kc)
        bkw[jt][kc] = gfrag(kvwk + (h32 + jt * 16 + lr) * 128 + kc * 32 + lg * 8);
#pragma unroll
    for (int mt = 0; mt < 4; ++mt) {
      f32x4 c0 = {0.f, 0.f, 0.f, 0.f}, c1 = {0.f, 0.f, 0.f, 0.f};
#pragma unroll
      for (int kc = 0; kc < 4; ++kc) {
        u32x4 ax = ldsfrag(smem + RX2, mt * 16 + lr, kc * 64 + lg * 16, 256);
        mfma16(c0, ax, bkw[0][kc]);
        mfma16(c1, ax, bkw[1][kc]);
      }
      float s[4];
#pragma unroll
      for (int i = 0; i < 4; ++i) s[i] = c0[i] * c0[i] + c1[i] * c1[i];
#pragma unroll
      for (int m = 1; m < 16; m <<= 1)
#pragma unroll
        for (int i = 0; i < 4; ++i) s[i] += __shfl_xor(s[i], m, 64);
#pragma unroll
      for (int i = 0; i < 4; ++i) {
        float rn = 1.0f / fmaxf(sqrtf(s[i]), 1e-12f);
        bnc32_st(bnc, lg * 4 + i, lr * 2, f2h(c0[i] * rn));
        bnc32_st(bnc, lg * 4 + i, (16 + lr) * 2, f2h(c1[i] * rn));
      }
      bk[mt] = bnc32_ld(bnc, lr, lg * 16);  // wave-local RAW
    }
  }
  __syncthreads();  // (2) all waves done reading x2 -> O may overlay RX2

  // ---- Q + attention per nt (swapped QK; no cross-32-lane shuffles) ----
  const float sc = scales[wv];  // includes log2(e)
  const float qb0 = qb[h32 + lr], qb1 = qb[h32 + 16 + lr];
#pragma unroll
  for (int nt = 0; nt < 4; ++nt) {
    f32x4 q0 = {0.f, 0.f, 0.f, 0.f}, q1 = {0.f, 0.f, 0.f, 0.f};
#pragma unroll
    for (int kc = 0; kc < 4; ++kc) {
      u32x4 a = ldsfrag(smem + RX1, nt * 16 + lr, kc * 64 + lg * 16, 256);
      u32x4 w0 = gfrag(qw_ + (h32 + lr) * 128 + kc * 32 + lg * 8);
      u32x4 w1 = gfrag(qw_ + (h32 + 16 + lr) * 128 + kc * 32 + lg * 8);
      mfma16(q0, a, w0);
      mfma16(q1, a, w1);
    }
    // bias + L2-norm via PROVEN mask-1/2/4/8 tree (R14 verbatim), store q̂
    float s[4];
#pragma unroll
    for (int i = 0; i < 4; ++i) {
      q0[i] += qb0; q1[i] += qb1;
      s[i] = q0[i] * q0[i] + q1[i] * q1[i];
    }
#pragma unroll
    for (int m = 1; m < 16; m <<= 1)
#pragma unroll
      for (int i = 0; i < 4; ++i) s[i] += __shfl_xor(s[i], m, 64);
#pragma unroll
    for (int i = 0; i < 4; ++i) {
      float rn = 1.0f / fmaxf(sqrtf(s[i]), 1e-12f);
      bnc32_st(bnc, lg * 4 + i, lr * 2, f2h(q0[i] * rn));
      bnc32_st(bnc, lg * 4 + i, (16 + lr) * 2, f2h(q1[i] * rn));
    }
    u32x4 aq = bnc32_ld(bnc, lr, lg * 16);  // wave-local RAW; normalized q, token=lr

    // swapped QK: p4[mt][i] = cos[k = mt*16+lg*4+i][q = lr]
    f32x4 p4[4];
#pragma unroll
    for (int mt = 0; mt < 4; ++mt) {
      f32x4 z = {0.f, 0.f, 0.f, 0.f};
      mfma16(z, bk[mt], aq);
      p4[mt] = z;
    }
    // exp (constant bound sc) + lane-local partial sum
    float psum = 0.f;
#pragma unroll
    for (int mt = 0; mt < 4; ++mt)
#pragma unroll
      for (int i = 0; i < 4; ++i) {
        float p = exp2f(fmaf(p4[mt][i], sc, -sc));
        p4[mt][i] = p;
        psum += p;
      }
    // lg-group sum via wave-private LDS exchange (in-order DS; no 16/32 shfl)
    *(float*)(pex + lr * 16 + lg * 4) = psum;
    float4 ps = *(const float4*)(pex + lr * 16);
    const float rs = 1.0f / (ps.x + ps.y + ps.z + ps.w);

    // P -> strip [row = q local = lr][col = m], stride 128 swz
#pragma unroll
    for (int mt = 0; mt < 4; ++mt)
#pragma unroll
      for (int i = 0; i < 4; ++i)
        lds_st16(bnc, lr, (mt * 16 + lg * 4 + i) * 2, 128, f2h(p4[mt][i] * rs));

    // ap read: round-14 verbatim (row = lr, m = kc*32 + lg*8 + j)
    u32x4 ap[2];
#pragma unroll
    for (int kc = 0; kc < 2; ++kc)
      ap[kc] = ldsfrag(bnc, lr, kc * 64 + lg * 16, 128);  // wave-local RAW
#pragma unroll
    for (int ct = 0; ct < 2; ++ct) {
      f32x4 z = {0.f, 0.f, 0.f, 0.f};
#pragma unroll
      for (int kc = 0; kc < 2; ++kc) mfma16(z, ap[kc], bv[ct][kc]);
#pragma unroll
      for (int i = 0; i < 4; ++i)
        lds_st16(smem + RX2, nt * 16 + lg * 4 + i, (h32 + ct * 16 + lr) * 2, 256,
                 f2h(z[i]));
    }
  }

  // hoist proj weight frags (L2) to overlap with the barrier
  u32x4 bp[2][4];
#pragma unroll
  for (int ct = 0; ct < 2; ++ct)
#pragma unroll
    for (int kc = 0; kc < 4; ++kc)
      bp[ct][kc] = gfrag(pw_ + (h32 + ct * 16 + lr) * 128 + kc * 32 + lg * 8);
  float pbv[2] = { pb[h32 + lr], pb[h32 + 16 + lr] };

  __syncthreads();  // (3) O complete

  // ---- proj (column-scheme): out[:, h32..h32+32) = O @ pw[own rows]^T + pb ----
  {
    float* ob = out + (size_t)b * 8192;
#pragma unroll
    for (int np = 0; np < 2; ++np) {
      u32x4 af[2][4];
#pragma unroll
      for (int t = 0; t < 2; ++t)
#pragma unroll
        for (int kc = 0; kc < 4; ++kc)
          af[t][kc] = ldsfrag(smem + RX2, (np * 2 + t) * 16 + lr, kc * 64 + lg * 16, 256);
#pragma unroll
      for (int t = 0; t < 2; ++t)
#pragma unroll
        for (int ct = 0; ct < 2; ++ct) {
          f32x4 acc = {0.f, 0.f, 0.f, 0.f};
#pragma unroll
          for (int kc = 0; kc < 4; ++kc) mfma16(acc, af[t][kc], bp[ct][kc]);
#pragma unroll
          for (int i = 0; i < 4; ++i) {
            int row = (np * 2 + t) * 16 + lg * 4 + i;
            ob[row * 128 + h32 + ct * 16 + lr] = acc[i] + pbv[ct];
          }
        }
    }
  }
}

extern "C" void kernel_launch(void* const* d_in, const int* in_sizes, int n_in,
                              void* d_out, int out_size, void* d_ws, size_t ws_size,
                              hipStream_t stream) {
  const float* x1 = (const float*)d_in[0];
  const float* x2 = (const float*)d_in[1];
  const float* qw = (const float*)d_in[2];
  const float* qb = (const float*)d_in[3];
  const float* kvw = (const float*)d_in[4];
  const float* vb = (const float*)d_in[5];
  const float* ls = (const float*)d_in[6];
  const float* pw = (const float*)d_in[7];
  const float* pb = (const float*)d_in[8];
  u16* wh = (u16*)d_ws;                           // 65536 f16 = 128 KB
  float* scales = (float*)((char*)d_ws + 131072); // 4 floats

  wca_prep<<<64, 256, 0, stream>>>(qw, kvw, pw, ls, wh, scales);
  wca_kernel<<<NWIN, 256, 0, stream>>>(x1, x2, qb, vb, pb, wh, scales, (float*)d_out);
}

// Round 18
// 288.327 us; speedup vs baseline: 2.9251x; 1.0623x over previous
//
#include <hip/hip_runtime.h>

typedef float f32x4 __attribute__((ext_vector_type(4)));
typedef unsigned int u32x4 __attribute__((ext_vector_type(4)));
typedef _Float16 f16x8 __attribute__((ext_vector_type(8)));
typedef unsigned short u16;
typedef unsigned int u32;

// ---- constants ----
#define NWIN 8192
#define MAX_LOG_SCALE 4.605170185988091f  // log(100)
#define LOG2E 1.4426950408889634f

// Wave = head end-to-end; 3 barriers; launch_bounds(256,4) (reg-pinned ~128
// unified regs/wave; tighter caps spill — rounds 4/6/10/12).
// Round 18 = round 17 (306 us) + three safe micro-cuts:
//  (1) P strip store packed: 16x ds_write_b16 -> 4x 8-byte stores per nt
//      (4 consecutive columns per (mt,lg) fit one swz granule)
//  (2) V pass jt-loops merged so each x2 fragment is read ONCE (-16 b128/wave)
//  (3) nt-invariant qw weight frags hoisted out of the attention loop
// PLATFORM RULE (R15/R16 forensics): __shfl_* across the 32-lane boundary
// (masks 16/32) produces wrong results — use LDS exchange (pex) instead.
// LDS (40 KB -> 4 blocks/CU):
//   RX1  [0,16K):   x1 f16 [64][128] swz
//   RX2  [16K,32K): x2 f16 [64][128] swz -> O overlay after barrier (2)
//   RBNC [32K,40K): per-wave 2 KB strip (vT -> k -> q -> P + pex@1792)
#define RX1 0
#define RX2 16384
#define RBNC 32768
#define LDS_BYTES 40960

__device__ __forceinline__ void mfma16(f32x4& acc, u32x4 a, u32x4 b) {
  acc = __builtin_amdgcn_mfma_f32_16x16x32_f16(
      __builtin_bit_cast(f16x8, a), __builtin_bit_cast(f16x8, b), acc, 0, 0, 0);
}

__device__ __forceinline__ u16 f2h(float f) {
  return __builtin_bit_cast(u16, (_Float16)f);
}
__device__ __forceinline__ u32 pkh(float x, float y) {  // packed f32->f16 (RTZ)
  return __builtin_bit_cast(u32, __builtin_amdgcn_cvt_pkrtz(x, y));
}

// XOR swizzle within a row (row stride 256B or 128B); bijective, stays in-row.
__device__ __forceinline__ int swz(int row, int colbyte) {
  return colbyte ^ ((row & 7) << 4);
}
__device__ __forceinline__ u32x4 ldsfrag(const char* p, int row, int colbyte, int stride) {
  return *(const u32x4*)(p + row * stride + swz(row, colbyte));
}
__device__ __forceinline__ void lds_st16(char* p, int row, int colbyte, int stride, u16 v) {
  *(u16*)(p + row * stride + swz(row, colbyte)) = v;
}
// small bounce [16][32] f16: padded stride 80B (banks spread, no swizzle)
__device__ __forceinline__ u32x4 bnc32_ld(const char* p, int row, int colbyte) {
  return *(const u32x4*)(p + row * 80 + colbyte);
}
__device__ __forceinline__ void bnc32_st(char* p, int row, int colbyte, u16 v) {
  *(u16*)(p + row * 80 + colbyte) = v;
}
__device__ __forceinline__ u32x4 gfrag(const u16* p) {
  return *(const u32x4*)p;
}

// ---------- weight prep: f32 -> f16 (contiguous qw|kvw|pw) + head scales ----------
__global__ void wca_prep(const float* __restrict__ qw, const float* __restrict__ kvw,
                         const float* __restrict__ pw, const float* __restrict__ ls,
                         u16* __restrict__ wh, float* __restrict__ scales) {
  int t = blockIdx.x * 256 + threadIdx.x;   // 0..16383, one float4 each
  int e = t * 4;
  const float* src;
  int off;
  if (e < 16384)      { src = qw;  off = e; }
  else if (e < 49152) { src = kvw; off = e - 16384; }
  else                { src = pw;  off = e - 49152; }
  float4 v = *(const float4*)(src + off);
  uint2 o = { pkh(v.x, v.y), pkh(v.z, v.w) };
  *(uint2*)(wh + e) = o;
  if (t < 4) scales[t] = __expf(fminf(ls[t], MAX_LOG_SCALE)) * LOG2E;
}

// ---------- main kernel: one window per block, wave = head, 3 barriers ----------
__global__ void __launch_bounds__(256, 4) wca_kernel(
    const float* __restrict__ x1, const float* __restrict__ x2,
    const float* __restrict__ qb, const float* __restrict__ vb,
    const float* __restrict__ pb, const u16* __restrict__ wh,
    const float* __restrict__ scales, float* __restrict__ out) {
  __shared__ char smem[LDS_BYTES];
  const int b = blockIdx.x;
  const int tid = threadIdx.x;
  const int wv = tid >> 6;          // wave = head 0..3
  const int lane = tid & 63;
  const int lr = lane & 15;
  const int lg = lane >> 4;
  const int h32 = wv * 32;
  const u16* qw_  = wh;                     // 128x128
  const u16* kvwk = wh + 16384;             // k-part rows 0..127
  const u16* kvwv = wh + 16384 + 16384;     // v-part rows 0..127
  const u16* pw_  = wh + 49152;             // 128x128
  char* bnc = smem + RBNC + wv * 2048;      // wave-private bounce strip
  char* pex = bnc + 1792;                   // 256B partial-sum exchange area

  // ---- phase 0: stage x1 AND x2 -> f16 LDS (all 16 loads hoisted) ----
  {
    const float4* p1 = (const float4*)(x1 + (size_t)b * 8192);
    const float4* p2 = (const float4*)(x2 + (size_t)b * 8192);
    float4 a[8], c[8];
#pragma unroll
    for (int i = 0; i < 8; ++i) { a[i] = p1[i * 256 + tid]; c[i] = p2[i * 256 + tid]; }
#pragma unroll
    for (int i = 0; i < 8; ++i) {
      int e = (i * 256 + tid) * 4;
      int row = e >> 7;
      int colb = (e & 127) * 2;
      uint2 pa = { pkh(a[i].x, a[i].y), pkh(a[i].z, a[i].w) };
      uint2 pc = { pkh(c[i].x, c[i].y), pkh(c[i].z, c[i].w) };
      *(uint2*)(smem + RX1 + row * 256 + swz(row, colb)) = pa;
      *(uint2*)(smem + RX2 + row * 256 + swz(row, colb)) = pc;
    }
  }
  __syncthreads();  // (1) x1,x2 visible

  // ---- V pass: vT(c,m) = sum_k kvw_v[h32+c][k]*x2[m][k] + vb ----
  // jt loops merged: each x2 fragment read once, feeds both jt accumulators.
  u32x4 bv[2][2];
  {
    u32x4 akv[2][4];
#pragma unroll
    for (int jt = 0; jt < 2; ++jt)
#pragma unroll
      for (int kc = 0; kc < 4; ++kc)
        akv[jt][kc] = gfrag(kvwv + (h32 + jt * 16 + lr) * 128 + kc * 32 + lg * 8);
    f32x4 vc[2][4];
#pragma unroll
    for (int jt = 0; jt < 2; ++jt)
#pragma unroll
      for (int nt = 0; nt < 4; ++nt) vc[jt][nt] = (f32x4){0.f, 0.f, 0.f, 0.f};
#pragma unroll
    for (int nt = 0; nt < 4; ++nt) {
      u32x4 bx[4];
#pragma unroll
      for (int kc = 0; kc < 4; ++kc)
        bx[kc] = ldsfrag(smem + RX2, nt * 16 + lr, kc * 64 + lg * 16, 256);
#pragma unroll
      for (int jt = 0; jt < 2; ++jt)
#pragma unroll
        for (int kc = 0; kc < 4; ++kc) mfma16(vc[jt][nt], akv[jt][kc], bx[kc]);
    }
    // per jt: bias + bounce through the (single) strip, then bv frags
#pragma unroll
    for (int jt = 0; jt < 2; ++jt) {
      float vbias[4];
#pragma unroll
      for (int i = 0; i < 4; ++i) vbias[i] = vb[h32 + jt * 16 + lg * 4 + i];
#pragma unroll
      for (int nt = 0; nt < 4; ++nt)
#pragma unroll
        for (int i = 0; i < 4; ++i)
          lds_st16(bnc, lg * 4 + i, (nt * 16 + lr) * 2, 128,
                   f2h(vc[jt][nt][i] + vbias[i]));
#pragma unroll
      for (int kc = 0; kc < 2; ++kc)
        bv[jt][kc] = ldsfrag(bnc, lr, kc * 64 + lg * 16, 128);  // wave-local RAW
    }
  }

  // ---- K pass: k rows m, L2-normalized -> bk[mt] ----
  u32x4 bk[4];
  {
    u32x4 bkw[2][4];
#pragma unroll
    for (int jt = 0; jt < 2; ++jt)
#pragma unroll
      for (int kc = 0; kc < 4; ++kc)
        bkw[jt][kc] = gfrag(kvwk + (h32 + jt * 16 + lr) * 128 + kc * 32 + lg * 8);
#pragma unroll
    for (int mt = 0; mt < 4; ++mt) {
      f32x4 c0 = {0.f, 0.f, 0.f, 0.f}, c1 = {0.f, 0.f, 0.f, 0.f};
#pragma unroll
      for (int kc = 0; kc < 4; ++kc) {
        u32x4 ax = ldsfrag(smem + RX2, mt * 16 + lr, kc * 64 + lg * 16, 256);
        mfma16(c0, ax, bkw[0][kc]);
        mfma16(c1, ax, bkw[1][kc]);
      }
      float s[4];
#pragma unroll
      for (int i = 0; i < 4; ++i) s[i] = c0[i] * c0[i] + c1[i] * c1[i];
#pragma unroll
      for (int m = 1; m < 16; m <<= 1)
#pragma unroll
        for (int i = 0; i < 4; ++i) s[i] += __shfl_xor(s[i], m, 64);
#pragma unroll
      for (int i = 0; i < 4; ++i) {
        float rn = 1.0f / fmaxf(sqrtf(s[i]), 1e-12f);
        bnc32_st(bnc, lg * 4 + i, lr * 2, f2h(c0[i] * rn));
        bnc32_st(bnc, lg * 4 + i, (16 + lr) * 2, f2h(c1[i] * rn));
      }
      bk[mt] = bnc32_ld(bnc, lr, lg * 16);  // wave-local RAW
    }
  }
  __syncthreads();  // (2) all waves done reading x2 -> O may overlay RX2

  // ---- Q + attention per nt (swapped QK; qw frags hoisted; packed P store) ----
  const float sc = scales[wv];  // includes log2(e)
  const float qb0 = qb[h32 + lr], qb1 = qb[h32 + 16 + lr];
  u32x4 qwf[2][4];              // nt-invariant q-weight frags (L2, hoisted)
#pragma unroll
  for (int kc = 0; kc < 4; ++kc) {
    qwf[0][kc] = gfrag(qw_ + (h32 + lr) * 128 + kc * 32 + lg * 8);
    qwf[1][kc] = gfrag(qw_ + (h32 + 16 + lr) * 128 + kc * 32 + lg * 8);
  }
#pragma unroll
  for (int nt = 0; nt < 4; ++nt) {
    f32x4 q0 = {0.f, 0.f, 0.f, 0.f}, q1 = {0.f, 0.f, 0.f, 0.f};
#pragma unroll
    for (int kc = 0; kc < 4; ++kc) {
      u32x4 a = ldsfrag(smem + RX1, nt * 16 + lr, kc * 64 + lg * 16, 256);
      mfma16(q0, a, qwf[0][kc]);
      mfma16(q1, a, qwf[1][kc]);
    }
    // bias + L2-norm via PROVEN mask-1/2/4/8 tree, store q̂
    float s[4];
#pragma unroll
    for (int i = 0; i < 4; ++i) {
      q0[i] += qb0; q1[i] += qb1;
      s[i] = q0[i] * q0[i] + q1[i] * q1[i];
    }
#pragma unroll
    for (int m = 1; m < 16; m <<= 1)
#pragma unroll
      for (int i = 0; i < 4; ++i) s[i] += __shfl_xor(s[i], m, 64);
#pragma unroll
    for (int i = 0; i < 4; ++i) {
      float rn = 1.0f / fmaxf(sqrtf(s[i]), 1e-12f);
      bnc32_st(bnc, lg * 4 + i, lr * 2, f2h(q0[i] * rn));
      bnc32_st(bnc, lg * 4 + i, (16 + lr) * 2, f2h(q1[i] * rn));
    }
    u32x4 aq = bnc32_ld(bnc, lr, lg * 16);  // wave-local RAW; normalized q, token=lr

    // swapped QK: p4[mt][i] = cos[k = mt*16+lg*4+i][q = lr]
    f32x4 p4[4];
#pragma unroll
    for (int mt = 0; mt < 4; ++mt) {
      f32x4 z = {0.f, 0.f, 0.f, 0.f};
      mfma16(z, bk[mt], aq);
      p4[mt] = z;
    }
    // exp (constant bound sc) + lane-local partial sum
    float psum = 0.f;
#pragma unroll
    for (int mt = 0; mt < 4; ++mt)
#pragma unroll
      for (int i = 0; i < 4; ++i) {
        float p = exp2f(fmaf(p4[mt][i], sc, -sc));
        p4[mt][i] = p;
        psum += p;
      }
    // lg-group sum via wave-private LDS exchange (NO cross-32 shfl)
    *(float*)(pex + lr * 16 + lg * 4) = psum;
    float4 ps = *(const float4*)(pex + lr * 16);
    const float rs = 1.0f / (ps.x + ps.y + ps.z + ps.w);

    // P -> strip [row=q=lr][col=m], stride 128 swz; PACKED 8-byte stores
    // (4 consecutive m per (mt,lg): colb = mt*32+lg*8, colb%16 in {0,8})
#pragma unroll
    for (int mt = 0; mt < 4; ++mt) {
      uint2 pp = { pkh(p4[mt][0] * rs, p4[mt][1] * rs),
                   pkh(p4[mt][2] * rs, p4[mt][3] * rs) };
      int colb = mt * 32 + lg * 8;
      *(uint2*)(bnc + lr * 128 + swz(lr, colb)) = pp;
    }

    // ap read (row = lr, m = kc*32 + lg*8 + j)
    u32x4 ap[2];
#pragma unroll
    for (int kc = 0; kc < 2; ++kc)
      ap[kc] = ldsfrag(bnc, lr, kc * 64 + lg * 16, 128);  // wave-local RAW
#pragma unroll
    for (int ct = 0; ct < 2; ++ct) {
      f32x4 z = {0.f, 0.f, 0.f, 0.f};
#pragma unroll
      for (int kc = 0; kc < 2; ++kc) mfma16(z, ap[kc], bv[ct][kc]);
#pragma unroll
      for (int i = 0; i < 4; ++i)
        lds_st16(smem + RX2, nt * 16 + lg * 4 + i, (h32 + ct * 16 + lr) * 2, 256,
                 f2h(z[i]));
    }
  }

  // hoist proj weight frags (L2) to overlap with the barrier
  u32x4 bp[2][4];
#pragma unroll
  for (int ct = 0; ct < 2; ++ct)
#pragma unroll
    for (int kc = 0; kc < 4; ++kc)
      bp[ct][kc] = gfrag(pw_ + (h32 + ct * 16 + lr) * 128 + kc * 32 + lg * 8);
  float pbv[2] = { pb[h32 + lr], pb[h32 + 16 + lr] };

  __syncthreads();  // (3) O complete

  // ---- proj (column-scheme): out[:, h32..h32+32) = O @ pw[own rows]^T + pb ----
  {
    float* ob = out + (size_t)b * 8192;
#pragma unroll
    for (int np = 0; np < 2; ++np) {
      u32x4 af[2][4];
#pragma unroll
      for (int t = 0; t < 2; ++t)
#pragma unroll
        for (int kc = 0; kc < 4; ++kc)
          af[t][kc] = ldsfrag(smem + RX2, (np * 2 + t) * 16 + lr, kc * 64 + lg * 16, 256);
#pragma unroll
      for (int t = 0; t < 2; ++t)
#pragma unroll
        for (int ct = 0; ct < 2; ++ct) {
          f32x4 acc = {0.f, 0.f, 0.f, 0.f};
#pragma unroll
          for (int kc = 0; kc < 4; ++kc) mfma16(acc, af[t][kc], bp[ct][kc]);
#pragma unroll
          for (int i = 0; i < 4; ++i) {
            int row = (np * 2 + t) * 16 + lg * 4 + i;
            ob[row * 128 + h32 + ct * 16 + lr] = acc[i] + pbv[ct];
          }
        }
    }
  }
}

extern "C" void kernel_launch(void* const* d_in, const int* in_sizes, int n_in,
                              void* d_out, int out_size, void* d_ws, size_t ws_size,
                              hipStream_t stream) {
  const float* x1 = (const float*)d_in[0];
  const float* x2 = (const float*)d_in[1];
  const float* qw = (const float*)d_in[2];
  const float* qb = (const float*)d_in[3];
  const float* kvw = (const float*)d_in[4];
  const float* vb = (const float*)d_in[5];
  const float* ls = (const float*)d_in[6];
  const float* pw = (const float*)d_in[7];
  const float* pb = (const float*)d_in[8];
  u16* wh = (u16*)d_ws;                           // 65536 f16 = 128 KB
  float* scales = (float*)((char*)d_ws + 131072); // 4 floats

  wca_prep<<<64, 256, 0, stream>>>(qw, kvw, pw, ls, wh, scales);
  wca_kernel<<<NWIN, 256, 0, stream>>>(x1, x2, qb, vb, pb, wh, scales, (float*)d_out);
}